// Round 12
// baseline (43.030 us; speedup 1.0000x reference)
//
#include <hip/hip_runtime.h>
#include <hip/hip_bf16.h>

#define EPSF 1e-5f
// fold (1/sqrt(2)) * log2(e) into q so score feeds v_exp_f32 (exp2) directly
#define QSCALE 1.0201606003163899f

typedef float v2f __attribute__((ext_vector_type(2)));
typedef float v4f __attribute__((ext_vector_type(4)));

#if __has_builtin(__builtin_amdgcn_exp2f)
#define EXP2F(x) __builtin_amdgcn_exp2f(x)
#else
extern "C" __device__ float __ocml_native_exp2_f32(float);
#define EXP2F(x) __ocml_native_exp2_f32(x)
#endif

__device__ __forceinline__ void two_qubit(float xa, float xb, float pa, float pb,
                                          float cg, float sg, float ch, float sh,
                                          float& z0, float& z1) {
    const float ha = 0.5f * (xa + pa);
    const float hb = 0.5f * (xb + pb);
    float sa, ca, sb, cb;
    __sincosf(ha, &sa, &ca);
    __sincosf(hb, &sb, &cb);
    const float p00 = ca * cb, p01 = ca * sb;
    const float p10 = sa * sb, p11 = sa * cb;  // post-CNOT
    const float q00 = cg * p00 - sg * p10;
    const float q10 = sg * p00 + cg * p10;
    const float q01 = cg * p01 - sg * p11;
    const float q11 = sg * p01 + cg * p11;
    const float r00 = ch * q00 - sh * q01;
    const float r01 = sh * q00 + ch * q01;
    const float r10 = ch * q10 - sh * q11;
    const float r11 = sh * q10 + ch * q11;
    const float a = r00 * r00, b = r01 * r01, c = r10 * r10, d = r11 * r11;
    z0 = a + b - c - d;
    z1 = a - b + c - d;
}

// ---------------- Kernel A: one wave per (image, head) ----------------
__global__ __launch_bounds__(64)
void quanv_attn(const float* __restrict__ x,
                const float* __restrict__ qparams,
                const float* __restrict__ in_w,
                const float* __restrict__ in_b,
                float2* __restrict__ ws)
{
    __shared__ __align__(16) float img[784];
    __shared__ v4f kT[98];   // kT[i] = (k0[2i],k0[2i+1],k1[2i],k1[2i+1])
    __shared__ v4f vT[98];
    __shared__ float w6[24], b6[6], qp_s[4], qc_s[8];

    const int lane = threadIdx.x;
    const int bid  = blockIdx.x;
    const int im   = bid >> 1;
    const int h    = bid & 1;

    // stage image + this head's weights
    const float4* xb4 = (const float4*)(x + (size_t)im * 784);
    #pragma unroll
    for (int r = 0; r < 3; ++r) ((float4*)img)[lane + 64 * r] = xb4[lane + 64 * r];
    if (lane < 4) ((float4*)img)[192 + lane] = xb4[192 + lane];
    if (lane < 24) {
        const int j6 = lane >> 2;   // 0..5 -> rows {2h,2h+1,4+2h,5+2h,8+2h,9+2h}
        w6[lane] = in_w[((j6 >> 1) * 4 + 2 * h + (j6 & 1)) * 4 + (lane & 3)];
    }
    { int t = lane - 24; if (t >= 0 && t < 6)  b6[t] = in_b[(t >> 1) * 4 + 2 * h + (t & 1)]; }
    { int t = lane - 32; if (t >= 0 && t < 4)  qp_s[t] = qparams[t]; }
    { int t = lane - 40;
      if (t >= 0 && t < 4) {
          const float g = 0.5f * qparams[4 + t];
          float sg, cg;
          __sincosf(g, &sg, &cg);
          qc_s[2 * t] = cg; qc_s[2 * t + 1] = sg;
      } }
    __syncthreads();    // 1 wave: ~free

    // quantum features + this head's qkv; q stays in registers (lane owns rows)
    float qx[4], qy[4];
    #pragma unroll
    for (int r = 0; r < 4; ++r) {
        const int l = (r < 3) ? (lane + 64 * r) : (192 + lane);
        if (r == 3 && lane >= 4) break;
        const int rr = l / 14, cc = l % 14;
        const float p0 = img[(2 * rr) * 28 + 2 * cc];
        const float p1 = img[(2 * rr) * 28 + 2 * cc + 1];
        const float p2 = img[(2 * rr + 1) * 28 + 2 * cc];
        const float p3 = img[(2 * rr + 1) * 28 + 2 * cc + 1];
        float z0, z1, z2, z3;
        two_qubit(p0, p1, qp_s[0], qp_s[1], qc_s[0], qc_s[1], qc_s[2], qc_s[3], z0, z1);
        two_qubit(p2, p3, qp_s[2], qp_s[3], qc_s[4], qc_s[5], qc_s[6], qc_s[7], z2, z3);
        float a[6];
        #pragma unroll
        for (int j = 0; j < 6; ++j)
            a[j] = b6[j] + z0 * w6[j * 4] + z1 * w6[j * 4 + 1]
                 + z2 * w6[j * 4 + 2] + z3 * w6[j * 4 + 3];
        qx[r] = a[0] * QSCALE;
        qy[r] = a[1] * QSCALE;
        const int i4 = l >> 1, e = l & 1;
        ((float*)&kT[i4])[e]     = a[2];
        ((float*)&kT[i4])[2 + e] = a[3];
        ((float*)&vT[i4])[e]     = a[4];
        ((float*)&vT[i4])[2 + e] = a[5];
    }
    __syncthreads();    // 1 wave: ~free

    // attention: full m-range (98 pair-iters), 3 rows/lane, uniform broadcasts
    {
        v2f sum2[3], ac0[3], ac1[3];
        #pragma unroll
        for (int r = 0; r < 3; ++r) {
            sum2[r] = (v2f){0.f, 0.f};
            ac0[r]  = (v2f){0.f, 0.f};
            ac1[r]  = (v2f){0.f, 0.f};
        }
        #pragma unroll 7
        for (int i = 0; i < 98; ++i) {
            const v4f kk = kT[i];
            const v4f vv = vT[i];
            const v2f kxy = kk.xy, kzw = kk.zw;
            const v2f vxy = vv.xy, vzw = vv.zw;
            #pragma unroll
            for (int r = 0; r < 3; ++r) {
                const v2f s = kxy * qx[r] + kzw * qy[r];
                v2f e;
                e.x = EXP2F(s.x);
                e.y = EXP2F(s.y);
                sum2[r] += e;
                ac0[r]  += e * vxy;
                ac1[r]  += e * vzw;
            }
        }
        #pragma unroll
        for (int r = 0; r < 3; ++r) {
            const int l = lane + 64 * r;
            const float sum = sum2[r].x + sum2[r].y;
            const float inv = 1.0f / sum;
            const float a0 = (ac0[r].x + ac0[r].y) * inv;
            const float a1 = (ac1[r].x + ac1[r].y) * inv;
            ws[(size_t)im * 392 + l * 2 + h] = make_float2(a0, a1);
        }
    }
    // tail rows 192..195: 16 lanes per row, q broadcast from owner lane
    {
        const int grp = lane >> 4, s16 = lane & 15;
        const int l = 192 + grp;
        const float tqx = __shfl(qx[3], grp);
        const float tqy = __shfl(qy[3], grp);
        v2f S = {0.f, 0.f}, A0 = {0.f, 0.f}, A1 = {0.f, 0.f};
        #pragma unroll
        for (int k = 0; k < 6; ++k) {
            const int i = s16 + 16 * k;
            const v4f kk = kT[i];
            const v4f vv = vT[i];
            const v2f s = kk.xy * tqx + kk.zw * tqy;
            v2f e;
            e.x = EXP2F(s.x);
            e.y = EXP2F(s.y);
            S  += e;
            A0 += e * vv.xy;
            A1 += e * vv.zw;
        }
        if (s16 < 2) {
            const int i = 96 + s16;
            const v4f kk = kT[i];
            const v4f vv = vT[i];
            const v2f s = kk.xy * tqx + kk.zw * tqy;
            v2f e;
            e.x = EXP2F(s.x);
            e.y = EXP2F(s.y);
            S  += e;
            A0 += e * vv.xy;
            A1 += e * vv.zw;
        }
        float sum = S.x + S.y;
        float a0  = A0.x + A0.y;
        float a1  = A1.x + A1.y;
        #pragma unroll
        for (int off = 1; off < 16; off <<= 1) {
            sum += __shfl_xor(sum, off);
            a0  += __shfl_xor(a0, off);
            a1  += __shfl_xor(a1, off);
        }
        if (s16 == 0) {
            const float inv = 1.0f / sum;
            ws[(size_t)im * 392 + l * 2 + h] = make_float2(a0 * inv, a1 * inv);
        }
    }
}

// ---------------- Kernel B: one wave per image ----------------
__global__ __launch_bounds__(64)
void quanv_tail(const float2* __restrict__ ws,
                const float* __restrict__ out_w,
                const float* __restrict__ out_b,
                const float* __restrict__ lnw,
                const float* __restrict__ lnb,
                const float* __restrict__ lin_w,
                const float* __restrict__ lin_b,
                float* __restrict__ out)
{
    __shared__ __align__(16) float flat[784];
    __shared__ float w_out[16], b_out[4], s_lnw[4], s_lnb[4], s_linb[10];

    const int lane = threadIdx.x;
    const int im   = blockIdx.x;

    if (lane < 16) w_out[lane] = out_w[lane];
    { int t = lane - 16; if (t >= 0 && t < 4)  b_out[t] = out_b[t]; }
    { int t = lane - 24; if (t >= 0 && t < 4)  s_lnw[t] = lnw[t]; }
    { int t = lane - 32; if (t >= 0 && t < 4)  s_lnb[t] = lnb[t]; }
    { int t = lane - 40; if (t >= 0 && t < 10) s_linb[t] = lin_b[t]; }
    __syncthreads();    // 1 wave: ~free

    const float4* ob4 = (const float4*)(ws + (size_t)im * 392);
    #pragma unroll
    for (int r = 0; r < 4; ++r) {
        const int l = lane + 64 * r;
        if (l < 196) {
            const float4 f = ob4[l];
            const float f0 = f.x, f1 = f.y, f2 = f.z, f3 = f.w;
            const float e0 = b_out[0] + f0 * w_out[0]  + f1 * w_out[1]  + f2 * w_out[2]  + f3 * w_out[3];
            const float e1 = b_out[1] + f0 * w_out[4]  + f1 * w_out[5]  + f2 * w_out[6]  + f3 * w_out[7];
            const float e2 = b_out[2] + f0 * w_out[8]  + f1 * w_out[9]  + f2 * w_out[10] + f3 * w_out[11];
            const float e3 = b_out[3] + f0 * w_out[12] + f1 * w_out[13] + f2 * w_out[14] + f3 * w_out[15];
            const float mu = 0.25f * (e0 + e1 + e2 + e3);
            const float d0 = e0 - mu, d1 = e1 - mu, d2 = e2 - mu, d3 = e3 - mu;
            const float var = 0.25f * (d0 * d0 + d1 * d1 + d2 * d2 + d3 * d3);
            const float rs = rsqrtf(var + EPSF);
            flat[0 * 196 + l] = d0 * rs * s_lnw[0] + s_lnb[0];
            flat[1 * 196 + l] = d1 * rs * s_lnw[1] + s_lnb[1];
            flat[2 * 196 + l] = d2 * rs * s_lnw[2] + s_lnb[2];
            flat[3 * 196 + l] = d3 * rs * s_lnw[3] + s_lnb[3];
        }
    }
    __syncthreads();    // 1 wave: ~free

    float part[10];
    #pragma unroll
    for (int j = 0; j < 10; ++j) part[j] = 0.f;
    #pragma unroll
    for (int r = 0; r < 4; ++r) {
        const int i = lane + 64 * r;
        if (i < 196) {
            const float4 f = ((const float4*)flat)[i];
            const float4* lw = (const float4*)lin_w + i;
            #pragma unroll
            for (int j = 0; j < 10; ++j) {
                const float4 w = lw[j * 196];
                part[j] += f.x * w.x + f.y * w.y + f.z * w.z + f.w * w.w;
            }
        }
    }
    #pragma unroll
    for (int j = 0; j < 10; ++j) {
        #pragma unroll
        for (int off = 32; off > 0; off >>= 1) part[j] += __shfl_down(part[j], off);
    }
    if (lane == 0) {
        float lg[10];
        float mx = -1e30f;
        #pragma unroll
        for (int j = 0; j < 10; ++j) {
            lg[j] = part[j] + s_linb[j];
            mx = fmaxf(mx, lg[j]);
        }
        float se = 0.f;
        #pragma unroll
        for (int j = 0; j < 10; ++j) se += __expf(lg[j] - mx);
        const float lse = mx + __logf(se);
        #pragma unroll
        for (int j = 0; j < 10; ++j) out[(size_t)im * 10 + j] = lg[j] - lse;
    }
}

extern "C" void kernel_launch(void* const* d_in, const int* in_sizes, int n_in,
                              void* d_out, int out_size, void* d_ws, size_t ws_size,
                              hipStream_t stream) {
    const float* x        = (const float*)d_in[0];
    const float* qparams  = (const float*)d_in[1];
    const float* in_w     = (const float*)d_in[2];
    const float* in_b     = (const float*)d_in[3];
    const float* out_w    = (const float*)d_in[4];
    const float* out_b    = (const float*)d_in[5];
    const float* lnw      = (const float*)d_in[6];
    const float* lnb      = (const float*)d_in[7];
    const float* lin_w    = (const float*)d_in[8];
    const float* lin_b    = (const float*)d_in[9];
    float* out            = (float*)d_out;
    float2* ws            = (float2*)d_ws;

    const int nimg = in_sizes[0] / 784;
    hipLaunchKernelGGL(quanv_attn, dim3(nimg * 2), dim3(64), 0, stream,
                       x, qparams, in_w, in_b, ws);
    hipLaunchKernelGGL(quanv_tail, dim3(nimg), dim3(64), 0, stream,
                       ws, out_w, out_b, lnw, lnb, lin_w, lin_b, out);
}

// Round 13
// 37.090 us; speedup vs baseline: 1.1602x; 1.1602x over previous
//
#include <hip/hip_runtime.h>
#include <hip/hip_bf16.h>

#define NTHREADS 256
#define EPSF 1e-5f
// fold (1/sqrt(2)) * log2(e) into q so score feeds v_exp_f32 (exp2) directly
#define QSCALE 1.0201606003163899f

typedef float v2f __attribute__((ext_vector_type(2)));
typedef float v4f __attribute__((ext_vector_type(4)));

#if __has_builtin(__builtin_amdgcn_exp2f)
#define EXP2F(x) __builtin_amdgcn_exp2f(x)
#else
extern "C" __device__ float __ocml_native_exp2_f32(float);
#define EXP2F(x) __ocml_native_exp2_f32(x)
#endif

__device__ __forceinline__ void two_qubit(float xa, float xb, float pa, float pb,
                                          float cg, float sg, float ch, float sh,
                                          float& z0, float& z1) {
    const float ha = 0.5f * (xa + pa);
    const float hb = 0.5f * (xb + pb);
    float sa, ca, sb, cb;
    __sincosf(ha, &sa, &ca);
    __sincosf(hb, &sb, &cb);
    // product state, then CNOT(0,1) swaps |10> <-> |11>
    const float p00 = ca * cb, p01 = ca * sb;
    const float p10 = sa * sb, p11 = sa * cb;  // post-swap
    const float q00 = cg * p00 - sg * p10;
    const float q10 = sg * p00 + cg * p10;
    const float q01 = cg * p01 - sg * p11;
    const float q11 = sg * p01 + cg * p11;
    const float r00 = ch * q00 - sh * q01;
    const float r01 = sh * q00 + ch * q01;
    const float r10 = ch * q10 - sh * q11;
    const float r11 = sh * q10 + ch * q11;
    const float a = r00 * r00, b = r01 * r01, c = r10 * r10, d = r11 * r11;
    z0 = a + b - c - d;
    z1 = a - b + c - d;
}

__global__ __launch_bounds__(NTHREADS)
void quanv_fused(const float* __restrict__ x,
                 const float* __restrict__ qparams,
                 const float* __restrict__ in_w,
                 const float* __restrict__ in_b,
                 const float* __restrict__ out_w,
                 const float* __restrict__ out_b,
                 const float* __restrict__ lnw,
                 const float* __restrict__ lnb,
                 const float* __restrict__ lin_w,
                 const float* __restrict__ lin_b,
                 float* __restrict__ out)
{
    // union buffer: img (staging, 784f) / partials (2352f) / flat (784f)
    // live ranges are made disjoint by __syncthreads + reg staging.
    __shared__ __align__(16) float uni[2352];
    __shared__ __align__(8)  float2 qs[2][196];   // (q0,q1) pre-scaled by QSCALE
    __shared__ v4f kT[2][98];   // kT[h][i] = (k0[2i],k0[2i+1],k1[2i],k1[2i+1])
    __shared__ v4f vT[2][98];
    __shared__ float w_in[48], b_in[12], w_out[16], b_out[4];
    __shared__ float s_lnw[4], s_lnb[4], s_linb[10];
    __shared__ float qc[8];             // cos/sin of qparams[4..7]/2
    __shared__ float qp[4];             // qparams[0..3]
    __shared__ float wsum[4][10];
    __shared__ float logits_s[10];
    __shared__ float lse_s;

    // partial views into uni: [h*392 + hs*196 + l]
    float* psum = uni;
    float* pa0  = uni + 784;
    float* pa1  = uni + 1568;

    const int tid = threadIdx.x;
    const int bid = blockIdx.x;

    // ---- stage image (float4) + weights into LDS ----
    const float4* xb4 = (const float4*)(x + (size_t)bid * 784);
    if (tid < 196) ((float4*)uni)[tid] = xb4[tid];
    if (tid < 48) w_in[tid] = in_w[tid];
    {
        int t = tid - 64;  if (t >= 0 && t < 12) b_in[t] = in_b[t];
        t = tid - 80;      if (t >= 0 && t < 16) w_out[t] = out_w[t];
        t = tid - 96;      if (t >= 0 && t < 4)  b_out[t] = out_b[t];
        t = tid - 112;     if (t >= 0 && t < 4)  s_lnw[t] = lnw[t];
        t = tid - 128;     if (t >= 0 && t < 4)  s_lnb[t] = lnb[t];
        t = tid - 144;     if (t >= 0 && t < 10) s_linb[t] = lin_b[t];
        t = tid - 160;     if (t >= 0 && t < 4)  qp[t] = qparams[t];
        t = tid - 176;
        if (t >= 0 && t < 4) {
            const float g = 0.5f * qparams[4 + t];
            float sg, cg;
            __sincosf(g, &sg, &cg);
            qc[2 * t] = cg;
            qc[2 * t + 1] = sg;
        }
    }
    __syncthreads();

    // ---- quantum features + QKV projection (thread per patch) ----
    if (tid < 196) {
        const int l = tid;
        const int r = l / 14, c = l % 14;
        const float p0 = uni[(2 * r) * 28 + 2 * c];
        const float p1 = uni[(2 * r) * 28 + 2 * c + 1];
        const float p2 = uni[(2 * r + 1) * 28 + 2 * c];
        const float p3 = uni[(2 * r + 1) * 28 + 2 * c + 1];
        float z0, z1, z2, z3;
        two_qubit(p0, p1, qp[0], qp[1], qc[0], qc[1], qc[2], qc[3], z0, z1);
        two_qubit(p2, p3, qp[2], qp[3], qc[4], qc[5], qc[6], qc[7], z2, z3);
        float a[12];
        #pragma unroll
        for (int j = 0; j < 12; ++j)
            a[j] = b_in[j] + z0 * w_in[j * 4] + z1 * w_in[j * 4 + 1]
                 + z2 * w_in[j * 4 + 2] + z3 * w_in[j * 4 + 3];
        qs[0][l] = make_float2(a[0] * QSCALE, a[1] * QSCALE);   // head 0
        qs[1][l] = make_float2(a[2] * QSCALE, a[3] * QSCALE);   // head 1
        const int i4 = l >> 1, e = l & 1;
        ((float*)&kT[0][i4])[e]     = a[4];
        ((float*)&kT[0][i4])[2 + e] = a[5];
        ((float*)&kT[1][i4])[e]     = a[6];
        ((float*)&kT[1][i4])[2 + e] = a[7];
        ((float*)&vT[0][i4])[e]     = a[8];
        ((float*)&vT[0][i4])[2 + e] = a[9];
        ((float*)&vT[1][i4])[e]     = a[10];
        ((float*)&vT[1][i4])[2 + e] = a[11];
    }
    __syncthreads();

    // ---- attention (bounded scores, exp2-folded) ----
    // wave wv: head h = wv>>1, m-half hs = wv&1 (pairs [hs*49, hs*49+49)).
    // Each lane owns rows {lane, lane+64, lane+128}; every kk/vv read is a
    // full-wave broadcast amortized over 3 rows. Partial (sum,a0,a1) per
    // (h,hs,row) goes to LDS; halves combined in the out-proj phase.
    const int wv = tid >> 6;
    const int lane = tid & 63;
    const int h = wv >> 1;
    const int hs = wv & 1;
    const int i0 = hs * 49;
    const int pbase = h * 392 + hs * 196;
    {
        float2 q[3];
        v2f sum2[3], ac0[3], ac1[3];
        #pragma unroll
        for (int r = 0; r < 3; ++r) {
            q[r] = qs[h][lane + r * 64];
            sum2[r] = (v2f){0.f, 0.f};
            ac0[r]  = (v2f){0.f, 0.f};
            ac1[r]  = (v2f){0.f, 0.f};
        }
        const v4f* kTp = &kT[h][i0];
        const v4f* vTp = &vT[h][i0];
        #pragma unroll 7
        for (int i = 0; i < 49; ++i) {
            const v4f kk = kTp[i];      // ds_read_b128, uniform broadcast
            const v4f vv = vTp[i];
            #pragma unroll
            for (int r = 0; r < 3; ++r) {
                const v2f s = kk.xy * q[r].x + kk.zw * q[r].y;
                v2f e;
                e.x = EXP2F(s.x);
                e.y = EXP2F(s.y);
                sum2[r] += e;
                ac0[r]  += e * vv.xy;
                ac1[r]  += e * vv.zw;
            }
        }
        #pragma unroll
        for (int r = 0; r < 3; ++r) {
            const int l = lane + r * 64;
            psum[pbase + l] = sum2[r].x + sum2[r].y;
            pa0[pbase + l]  = ac0[r].x + ac0[r].y;
            pa1[pbase + l]  = ac1[r].x + ac1[r].y;
        }
    }
    // tail rows 192..195: 16 lanes per row
    {
        const int g = lane >> 4, s16 = lane & 15;
        const int l = 192 + g;
        const float2 q = qs[h][l];
        const v4f* kTp = &kT[h][0];
        const v4f* vTp = &vT[h][0];
        v2f sum2 = {0.f, 0.f}, ac0 = {0.f, 0.f}, ac1 = {0.f, 0.f};
        #pragma unroll
        for (int k = 0; k < 3; ++k) {
            const int i = i0 + s16 + k * 16;
            const v4f kk = kTp[i];
            const v4f vv = vTp[i];
            const v2f s = kk.xy * q.x + kk.zw * q.y;
            v2f e;
            e.x = EXP2F(s.x);
            e.y = EXP2F(s.y);
            sum2 += e;
            ac0 += e * vv.xy;
            ac1 += e * vv.zw;
        }
        if (s16 == 0) {   // 49th pair
            const v4f kk = kTp[i0 + 48];
            const v4f vv = vTp[i0 + 48];
            const v2f s = kk.xy * q.x + kk.zw * q.y;
            v2f e;
            e.x = EXP2F(s.x);
            e.y = EXP2F(s.y);
            sum2 += e;
            ac0 += e * vv.xy;
            ac1 += e * vv.zw;
        }
        float sum = sum2.x + sum2.y;
        float a0  = ac0.x + ac0.y;
        float a1  = ac1.x + ac1.y;
        #pragma unroll
        for (int off = 1; off < 16; off <<= 1) {
            sum += __shfl_xor(sum, off);
            a0  += __shfl_xor(a0, off);
            a1  += __shfl_xor(a1, off);
        }
        if (s16 == 0) {
            psum[pbase + l] = sum;
            pa0[pbase + l]  = a0;
            pa1[pbase + l]  = a1;
        }
    }
    __syncthreads();

    // ---- combine halves -> regs, then out-proj + LayerNorm ----
    float f0, f1, f2, f3;
    if (tid < 196) {
        const int l = tid;
        const float s0 = psum[l]       + psum[196 + l];        // head 0
        const float s1 = psum[392 + l] + psum[588 + l];        // head 1
        const float i0h = 1.0f / s0, i1h = 1.0f / s1;
        f0 = (pa0[l]       + pa0[196 + l]) * i0h;
        f1 = (pa1[l]       + pa1[196 + l]) * i0h;
        f2 = (pa0[392 + l] + pa0[588 + l]) * i1h;
        f3 = (pa1[392 + l] + pa1[588 + l]) * i1h;
    }
    __syncthreads();   // all partial reads done before flat overwrites uni
    if (tid < 196) {
        const int l = tid;
        const float e0 = b_out[0] + f0 * w_out[0]  + f1 * w_out[1]  + f2 * w_out[2]  + f3 * w_out[3];
        const float e1 = b_out[1] + f0 * w_out[4]  + f1 * w_out[5]  + f2 * w_out[6]  + f3 * w_out[7];
        const float e2 = b_out[2] + f0 * w_out[8]  + f1 * w_out[9]  + f2 * w_out[10] + f3 * w_out[11];
        const float e3 = b_out[3] + f0 * w_out[12] + f1 * w_out[13] + f2 * w_out[14] + f3 * w_out[15];
        const float mu = 0.25f * (e0 + e1 + e2 + e3);
        const float d0 = e0 - mu, d1 = e1 - mu, d2 = e2 - mu, d3 = e3 - mu;
        const float var = 0.25f * (d0 * d0 + d1 * d1 + d2 * d2 + d3 * d3);
        const float rs = rsqrtf(var + EPSF);
        uni[0 * 196 + l] = d0 * rs * s_lnw[0] + s_lnb[0];
        uni[1 * 196 + l] = d1 * rs * s_lnw[1] + s_lnb[1];
        uni[2 * 196 + l] = d2 * rs * s_lnw[2] + s_lnb[2];
        uni[3 * 196 + l] = d3 * rs * s_lnw[3] + s_lnb[3];
    }
    __syncthreads();

    // ---- final linear (10 x 784), float4 per thread + log_softmax ----
    float part[10];
    #pragma unroll
    for (int j = 0; j < 10; ++j) part[j] = 0.f;
    if (tid < 196) {
        const float4 f = ((const float4*)uni)[tid];
        const float4* lw = (const float4*)lin_w + tid;
        #pragma unroll
        for (int j = 0; j < 10; ++j) {
            const float4 w = lw[j * 196];
            part[j] = f.x * w.x + f.y * w.y + f.z * w.z + f.w * w.w;
        }
    }
    #pragma unroll
    for (int j = 0; j < 10; ++j) {
        float v = part[j];
        #pragma unroll
        for (int off = 32; off > 0; off >>= 1) v += __shfl_down(v, off);
        if (lane == 0) wsum[wv][j] = v;
    }
    __syncthreads();
    if (tid < 10)
        logits_s[tid] = wsum[0][tid] + wsum[1][tid] + wsum[2][tid]
                      + wsum[3][tid] + s_linb[tid];
    __syncthreads();
    if (tid == 0) {
        float mx = logits_s[0];
        #pragma unroll
        for (int j = 1; j < 10; ++j) mx = fmaxf(mx, logits_s[j]);
        float se = 0.f;
        #pragma unroll
        for (int j = 0; j < 10; ++j) se += __expf(logits_s[j] - mx);
        lse_s = mx + __logf(se);
    }
    __syncthreads();
    if (tid < 10) out[(size_t)bid * 10 + tid] = logits_s[tid] - lse_s;
}

extern "C" void kernel_launch(void* const* d_in, const int* in_sizes, int n_in,
                              void* d_out, int out_size, void* d_ws, size_t ws_size,
                              hipStream_t stream) {
    const float* x        = (const float*)d_in[0];
    const float* qparams  = (const float*)d_in[1];
    const float* in_w     = (const float*)d_in[2];
    const float* in_b     = (const float*)d_in[3];
    const float* out_w    = (const float*)d_in[4];
    const float* out_b    = (const float*)d_in[5];
    const float* lnw      = (const float*)d_in[6];
    const float* lnb      = (const float*)d_in[7];
    const float* lin_w    = (const float*)d_in[8];
    const float* lin_b    = (const float*)d_in[9];
    float* out            = (float*)d_out;

    const int B = in_sizes[0] / 784;
    hipLaunchKernelGGL(quanv_fused, dim3(B), dim3(NTHREADS), 0, stream,
                       x, qparams, in_w, in_b, out_w, out_b, lnw, lnb, lin_w, lin_b, out);
}